// Round 13
// baseline (396.634 us; speedup 1.0000x reference)
//
#include <hip/hip_runtime.h>

// ---------------- problem constants ----------------
constexpr int N_NODES  = 50000;
constexpr int N_EDGES  = 800000;
constexpr int N_GRAPHS = 512;
constexpr int F_IN     = 128;
constexpr int HID      = 256;
constexpr int NPAD     = 50048;   // 391*128 padded rows
constexpr int NB_SCAN  = 49;      // scan blocks (1024 nodes each)

typedef short short8 __attribute__((ext_vector_type(8)));
typedef float f32x4  __attribute__((ext_vector_type(4)));

// bf16 helpers (raw ushort storage; RNE rounding)
__device__ __forceinline__ unsigned short f2b(float f) {
    unsigned u = __float_as_uint(f);
    u += 0x7fffu + ((u >> 16) & 1u);
    return (unsigned short)(u >> 16);
}
__device__ __forceinline__ float b2f_lo(unsigned u) { return __uint_as_float(u << 16); }
__device__ __forceinline__ float b2f_hi(unsigned u) { return __uint_as_float(u & 0xffff0000u); }

// ---------------- fused prep: deg histogram (+seq capture) + weights -> B-fragment ----------------
// seq[e] = this edge's per-destination ordinal (free byproduct of the histogram atomic).
// Wt_frag short index: half*(K*128) + ((k>>3)*128 + (n&127))*8 + (k&7), half = n>>7
__global__ __launch_bounds__(256) void prep_kernel(
    const int* __restrict__ dst, int* __restrict__ deg, int* __restrict__ seq,
    const float* __restrict__ W0, const float* __restrict__ W1, const float* __restrict__ W2,
    unsigned short* __restrict__ Wt0, unsigned short* __restrict__ Wt1, unsigned short* __restrict__ Wt2)
{
    const int b = blockIdx.x, t = threadIdx.x;
    if (b < 3125) {
        int e = b * 256 + t;                       // 3125*256 == 800000
        seq[e] = atomicAdd(&deg[dst[e]], 1);
    } else {
        int i = (b - 3125) * 256 + t;              // 640*256 == 163840
        const float* W; unsigned short* Wt; int K; int j;
        if (i < 32768)      { W = W0; Wt = Wt0; K = 128; j = i; }
        else if (i < 98304) { W = W1; Wt = Wt1; K = 256; j = i - 32768; }
        else                { W = W2; Wt = Wt2; K = 256; j = i - 98304; }
        int k = j >> 8, n = j & 255;
        int idx = (n >> 7) * (K * 128) + (((k >> 3) * 128 + (n & 127)) << 3) + (k & 7);
        Wt[idx] = f2b(W[j]);
    }
}

// ---------------- fused scan: 3 kernels -> 1 with a device-scope grid barrier ----------------
// 49 blocks x 1024 nodes. Stage 1: per-block degree sums + dis + bucket hist (publish via
// atomics -> coherent point, safe under XCD non-coherence). Grid barrier (fence + atomic
// arrive + spin; 49 blocks trivially co-resident). Stage 2 (redundant per block): 64-wide
// scans of bsum/bcnt read back via atomics. Stage 3: local node scan -> row_start, perm4
// {node,start,end,dis_bits} sorted by DESC degree, idx_of. bcur2 is a fresh zeroed
// per-bucket cursor (bucket bases derived from the bcnt scan).
__global__ __launch_bounds__(256) void scan_fused_kernel(
    const int* __restrict__ deg, float* __restrict__ dis,
    int* __restrict__ bcnt, int* __restrict__ bsum,
    int* __restrict__ bcur2, int* __restrict__ gbar,
    int* __restrict__ row_start, int4* __restrict__ perm4, int* __restrict__ idx_of, int n)
{
    __shared__ int sm[256];
    __shared__ int h64[64];     // stage1 LDS hist; stage2 bcnt inclusive scan
    __shared__ int horig[64];   // stage2 bcnt originals
    __shared__ int sscan[64];   // stage2 bsum inclusive scan
    __shared__ int lcnt[64], lbase[64];
    const int t = threadIdx.x, b = blockIdx.x, base = b * 1024;
    const int idx0 = base + t * 4;

    // ---- stage 1 ----
    if (t < 64) h64[t] = 0;
    __syncthreads();
    int v[4], s1 = 0;
    #pragma unroll
    for (int i = 0; i < 4; ++i) {
        int id = idx0 + i;
        v[i] = (id < n) ? deg[id] : 0; s1 += v[i];
        if (id < n) {
            dis[id] = rsqrtf((float)v[i] + 1.0f);
            atomicAdd(&h64[63 - min(v[i], 63)], 1);   // bucket 0 = heaviest
        }
    }
    sm[t] = s1; __syncthreads();
    for (int o = 128; o > 0; o >>= 1) { if (t < o) sm[t] += sm[t + o]; __syncthreads(); }
    if (t == 0) atomicExch(&bsum[b], sm[0]);          // coherent publish
    if (t < 64 && h64[t]) atomicAdd(&bcnt[t], h64[t]);

    // ---- grid barrier ----
    __threadfence();
    __syncthreads();
    if (t == 0) {
        atomicAdd(gbar, 1);
        while (atomicAdd(gbar, 0) < (int)gridDim.x) { }
    }
    __syncthreads();
    __threadfence();

    // ---- stage 2: redundant 64-wide scans (reads via atomics -> coherent) ----
    if (t < 64) {
        sscan[t] = (t < NB_SCAN) ? atomicAdd(&bsum[t], 0) : 0;
        int bc = atomicAdd(&bcnt[t], 0);
        horig[t] = bc; h64[t] = bc;
    }
    __syncthreads();
    for (int o = 1; o < 64; o <<= 1) {
        int a = (t >= o && t < 64) ? sscan[t - o] : 0;
        int c = (t >= o && t < 64) ? h64[t - o]  : 0;
        __syncthreads();
        if (t < 64) { sscan[t] += a; h64[t] += c; }
        __syncthreads();
    }
    const int myExcl = (b == 0) ? 0 : sscan[b - 1];   // edge-offset base for this block

    // ---- stage 3: local scans + outputs ----
    if (t < 64) lcnt[t] = 0;
    sm[t] = s1; __syncthreads();
    for (int o = 1; o < 256; o <<= 1) {
        int a = (t >= o) ? sm[t - o] : 0; __syncthreads();
        sm[t] += a; __syncthreads();
    }
    int excl = myExcl + sm[t] - s1;
    int st[4], lp[4];
    #pragma unroll
    for (int i = 0; i < 4; ++i) {
        int id = idx0 + i;
        st[i] = excl;
        if (id < n) {
            row_start[id] = excl;
            lp[i] = atomicAdd(&lcnt[63 - min(v[i], 63)], 1);
        }
        excl += v[i];
    }
    __syncthreads();
    if (t < 64) lbase[t] = lcnt[t] ? (h64[t] - horig[t]) + atomicAdd(&bcur2[t], lcnt[t]) : 0;
    __syncthreads();
    #pragma unroll
    for (int i = 0; i < 4; ++i) {
        int id = idx0 + i;
        if (id < n) {
            int hb = 63 - min(v[i], 63);
            int pos = lbase[hb] + lp[i];
            perm4[pos] = make_int4(id, st[i], st[i] + v[i],
                                   __float_as_int(rsqrtf((float)v[i] + 1.0f)));
            idx_of[id] = pos;
        }
    }
}

// ---------------- merged: CSR scatter (atomic-free via seq) + x -> bf16 half-major ----------------
// pos = row_start[d] + seq[e]: plain L2-resident loads replace the 800k cursor atomics.
__global__ __launch_bounds__(256) void fillcsr_xconv_kernel(
    const int* __restrict__ src, const int* __restrict__ dst,
    const float* __restrict__ dis, const int* __restrict__ idx_of,
    const int* __restrict__ row_start, const int* __restrict__ seq,
    int2* __restrict__ csr,
    const float* __restrict__ x, const int4* __restrict__ perm4,
    unsigned short* __restrict__ x_bf)
{
    const int b = blockIdx.x, t = threadIdx.x;
    if (b < 3125) {
        int e = b * 256 + t;                       // 3125*256 == 800000
        int s = src[e], d = dst[e];
        int pos = row_start[d] + seq[e];
        float w = dis[s] * dis[d];
        csr[pos] = make_int2(idx_of[s], __float_as_int(w));
    } else {
        int idx = (b - 3125) * 64 + (t >> 2);      // 782*64 >= NPAD
        if (idx >= N_NODES) return;
        int node = perm4[idx].x;
        int c = t & 3;                             // 32-feat chunk
        const float4* xs = reinterpret_cast<const float4*>(x + (size_t)node * 128 + c * 32);
        // half-major dest: half = c>>1, offset within half = (c&1)*32
        unsigned short* dp = x_bf + ((size_t)(c >> 1) * NPAD + idx) * 64 + (c & 1) * 32;
        #pragma unroll
        for (int u = 0; u < 8; ++u) {
            float4 v = xs[u];
            unsigned r0 = (unsigned)f2b(v.x) | ((unsigned)f2b(v.y) << 16);
            unsigned r1 = (unsigned)f2b(v.z) | ((unsigned)f2b(v.w) << 16);
            *reinterpret_cast<uint2*>(dp + u * 4) = make_uint2(r0, r1);
        }
    }
}

// ---------------- aggregation, feature-half partitioned (P=2, XCD-parity routed) ----------------
// hin half-major [2][NPAD][F/2] bf16. Half h = blockIdx&1 -> even/odd XCDs; per-XCD L2
// working set = F/2*2B*NPAD (6.4MB @F=128, 12.8MB @F=256).
// NO nontemporal hints anywhere: nt store cost +24MB WRITE (round 8), nt CSR load cost
// -13% gather rate + CSR re-fetch (round 9). Plain loads/stores throughout.
// 16 edges per wave-iter in both instantiations. Fragment-layout output.
template<int F>
__global__ __launch_bounds__(256) void agg_split(
    const unsigned short* __restrict__ hin, const int4* __restrict__ perm4,
    const int2* __restrict__ csr, uint4* __restrict__ out4)
{
    constexpr int ROW  = F / 2;       // feats per half-row: 128 / 64
    constexpr int LPR  = ROW / 8;     // lanes per half-row: 16 / 8
    constexpr int NSUB = 64 / LPR;    // subgroups per wave: 4 / 8
    constexpr int EPS  = 16 / NSUB;   // edges per subgroup per main iter: 4 / 2
    const int gid  = blockIdx.x;
    const int hh   = gid & 1;         // feature half, matches XCD parity
    const int nb   = gid >> 1;
    const int lane = threadIdx.x & 63;
    const int sub  = lane / LPR;
    const int fcl  = lane % LPR;      // 16B chunk within half
    const int idx  = nb * 4 + (threadIdx.x >> 6);
    if (idx >= N_NODES) return;
    const int4 p = perm4[idx];
    const float dn = __int_as_float(p.w);
    const unsigned short* hb = hin + (size_t)hh * NPAD * ROW;

    float acc[8];
    {   // self-loop term (sub 0 only covers the full half-row)
        float sw = (sub == 0) ? dn * dn : 0.0f;
        uint2 u2[2];
        *reinterpret_cast<uint4*>(u2) =
            *reinterpret_cast<const uint4*>(hb + (size_t)idx * ROW + fcl * 8);
        #pragma unroll
        for (int h = 0; h < 2; ++h) {
            acc[h * 4 + 0] = b2f_lo(u2[h].x) * sw;
            acc[h * 4 + 1] = b2f_hi(u2[h].x) * sw;
            acc[h * 4 + 2] = b2f_lo(u2[h].y) * sw;
            acc[h * 4 + 3] = b2f_hi(u2[h].y) * sw;
        }
    }

    int j = p.y;
    const int end = p.z;
    for (; j + 16 <= end; j += 16) {
        int2 c[EPS];
        uint2 g[EPS][2];
        #pragma unroll
        for (int u = 0; u < EPS; ++u) c[u] = csr[j + sub * EPS + u];
        #pragma unroll
        for (int u = 0; u < EPS; ++u)
            *reinterpret_cast<uint4*>(g[u]) =
                *reinterpret_cast<const uint4*>(hb + (size_t)c[u].x * ROW + fcl * 8);
        #pragma unroll
        for (int u = 0; u < EPS; ++u) {
            float w = __int_as_float(c[u].y);
            #pragma unroll
            for (int h = 0; h < 2; ++h) {
                acc[h * 4 + 0] = fmaf(b2f_lo(g[u][h].x), w, acc[h * 4 + 0]);
                acc[h * 4 + 1] = fmaf(b2f_hi(g[u][h].x), w, acc[h * 4 + 1]);
                acc[h * 4 + 2] = fmaf(b2f_lo(g[u][h].y), w, acc[h * 4 + 2]);
                acc[h * 4 + 3] = fmaf(b2f_hi(g[u][h].y), w, acc[h * 4 + 3]);
            }
        }
    }
    int jj = j + sub;
    for (; jj + NSUB < end; jj += 2 * NSUB) {
        int2 c0 = csr[jj], c1 = csr[jj + NSUB];
        uint2 g0[2], g1[2];
        *reinterpret_cast<uint4*>(g0) =
            *reinterpret_cast<const uint4*>(hb + (size_t)c0.x * ROW + fcl * 8);
        *reinterpret_cast<uint4*>(g1) =
            *reinterpret_cast<const uint4*>(hb + (size_t)c1.x * ROW + fcl * 8);
        float w0 = __int_as_float(c0.y), w1 = __int_as_float(c1.y);
        #pragma unroll
        for (int h = 0; h < 2; ++h) {
            acc[h * 4 + 0] = fmaf(b2f_lo(g0[h].x), w0, fmaf(b2f_lo(g1[h].x), w1, acc[h * 4 + 0]));
            acc[h * 4 + 1] = fmaf(b2f_hi(g0[h].x), w0, fmaf(b2f_hi(g1[h].x), w1, acc[h * 4 + 1]));
            acc[h * 4 + 2] = fmaf(b2f_lo(g0[h].y), w0, fmaf(b2f_lo(g1[h].y), w1, acc[h * 4 + 2]));
            acc[h * 4 + 3] = fmaf(b2f_hi(g0[h].y), w0, fmaf(b2f_hi(g1[h].y), w1, acc[h * 4 + 3]));
        }
    }
    if (jj < end) {
        int2 c0 = csr[jj];
        float w = __int_as_float(c0.y);
        uint2 g[2];
        *reinterpret_cast<uint4*>(g) =
            *reinterpret_cast<const uint4*>(hb + (size_t)c0.x * ROW + fcl * 8);
        #pragma unroll
        for (int h = 0; h < 2; ++h) {
            acc[h * 4 + 0] = fmaf(b2f_lo(g[h].x), w, acc[h * 4 + 0]);
            acc[h * 4 + 1] = fmaf(b2f_hi(g[h].x), w, acc[h * 4 + 1]);
            acc[h * 4 + 2] = fmaf(b2f_lo(g[h].y), w, acc[h * 4 + 2]);
            acc[h * 4 + 3] = fmaf(b2f_hi(g[h].y), w, acc[h * 4 + 3]);
        }
    }

    #pragma unroll
    for (int k = 0; k < 8; ++k) {
        #pragma unroll
        for (int off = LPR; off < 64; off <<= 1)
            acc[k] += __shfl_xor(acc[k], off, 64);
    }

    if (sub == 0) {
        uint2 r[2];
        #pragma unroll
        for (int h = 0; h < 2; ++h) {
            r[h].x = (unsigned)f2b(acc[h * 4 + 0]) | ((unsigned)f2b(acc[h * 4 + 1]) << 16);
            r[h].y = (unsigned)f2b(acc[h * 4 + 2]) | ((unsigned)f2b(acc[h * 4 + 3]) << 16);
        }
        int fc = hh * LPR + fcl;                   // global 16B chunk (0..F/8)
        int chunk = (idx >> 7) * (128 * (F / 8)) + fc * 128 + (idx & 127);
        out4[chunk] = *reinterpret_cast<uint4*>(r);
    }
}

// ---------------- MFMA GEMM, fragment-direct A, BOTH weight halves resident in LDS ----------------
// Merged column halves: one block per 128-row panel computes all 256 cols; A fragments
// loaded ONCE (halves the A read: was 2x per panel with grid-y=2). LDS = 2*K*128 ushorts
// (128KB @K=256 -- gfx950 LDS 160KB/CU, 1 block/CU). 4 waves: wm = rows{0,64}, wn = col-half.
// acc[4][8] (~128 acc regs + af 16 + bf 32: no spill expected).
template<int K>
__global__ __launch_bounds__(256) void gemm_frag(
    const uint4* __restrict__ A4,
    const unsigned short* __restrict__ Wt_frag,
    const float* __restrict__ bias,
    unsigned short* __restrict__ C,
    int relu)
{
    __shared__ __align__(16) unsigned short Bs[2 * K * 128];   // 128 KB (K=256) / 64 KB (K=128)
    const int t    = threadIdx.x;
    const int lane = t & 63;
    const int w    = t >> 6;
    const int wm   = w & 1, wn = w >> 1;
    const int q    = lane >> 4, m = lane & 15;
    const int panel = blockIdx.x;

    {   // stage BOTH weight halves: Wt_frag is [half][kchunk][col][8] contiguous
        const uint4* src4 = reinterpret_cast<const uint4*>(Wt_frag);
        uint4* dst4 = reinterpret_cast<uint4*>(Bs);
        #pragma unroll
        for (int it = 0; it < K / 8; ++it)       // 2*K*128/8 uint4 / 256 threads
            dst4[it * 256 + t] = src4[it * 256 + t];
    }
    __syncthreads();

    f32x4 acc[4][8] = {};
    const int abase = panel * (128 * (K / 8));
    const int bhalf = wn * (K * 128);            // ushort offset of this wave's col-half

    #pragma unroll
    for (int kb = 0; kb < K / 32; ++kb) {
        short8 af[4], bf[8];
        #pragma unroll
        for (int i = 0; i < 4; ++i) {
            uint4 v = A4[abase + (kb * 4 + q) * 128 + wm * 64 + i * 16 + m];
            af[i] = *reinterpret_cast<short8*>(&v);
        }
        #pragma unroll
        for (int jn = 0; jn < 8; ++jn)
            bf[jn] = *reinterpret_cast<const short8*>(
                &Bs[bhalf + (((kb * 4 + q) * 128 + jn * 16 + m) << 3)]);
        #pragma unroll
        for (int i = 0; i < 4; ++i)
            #pragma unroll
            for (int jn = 0; jn < 8; ++jn)
                acc[i][jn] = __builtin_amdgcn_mfma_f32_16x16x32_bf16(af[i], bf[jn], acc[i][jn], 0, 0, 0);
    }

    // epilogue: C/D layout col = lane&15, row = (lane>>4)*4 + reg; half-major bf16 out
    #pragma unroll
    for (int jn = 0; jn < 8; ++jn) {
        int col = wn * 128 + jn * 16 + m;
        float bj = bias[col];
        int ch = wn, cc = col & 127;
        #pragma unroll
        for (int i = 0; i < 4; ++i) {
            int rowb = panel * 128 + wm * 64 + i * 16 + q * 4;
            #pragma unroll
            for (int r = 0; r < 4; ++r) {
                float v = acc[i][jn][r] + bj;
                if (relu) v = fmaxf(v, 0.f);
                C[((size_t)ch * NPAD + (rowb + r)) * 128 + cc] = f2b(v);
            }
        }
    }
}

// ---------------- fused pool + MLP head: 512 threads ----------------
// Phase 1 (pooling): threads = 128 feature-pairs x 4 node-lanes; uint loads (2 bf16),
// 4 rows in flight per thread -> 16 rows/iter per block. Phase 2 (MLP): 256 feats x
// 2 k-halves (128 iters each). LDS mediates the phase remap.
__global__ __launch_bounds__(512) void pool_mlp_kernel(
    const unsigned short* __restrict__ h, const int* __restrict__ batch,
    const int* __restrict__ idx_of,
    const float* __restrict__ Wm1, const float* __restrict__ bm1,
    const float* __restrict__ Wm2, const float* __restrict__ bm2,
    float* __restrict__ out)
{
    __shared__ float psum[4][HID];     // phase1 partials; reused as [2][HID] in phase2
    __shared__ float p[HID];
    __shared__ float red[HID];
    __shared__ int se[2];
    const int g = blockIdx.x, t = threadIdx.x;
    if (t < 2) {
        int target = g + t;
        int lo = 0, hi = N_NODES;
        while (lo < hi) { int mid = (lo + hi) >> 1; if (batch[mid] < target) lo = mid + 1; else hi = mid; }
        se[t] = lo;
    }
    __syncthreads();
    const int s = se[0], e = se[1];

    // ---- phase 1: pooled sums ----
    const int fp = t & 127;            // feature pair: feats 2fp, 2fp+1
    const int pl = t >> 7;             // node lane 0..3
    const unsigned short* hp = h + (size_t)(fp >> 6) * ((size_t)NPAD * 128) + ((2 * fp) & 127);
    float a0 = 0.f, a1 = 0.f;
    int n = s + pl;
    for (; n + 12 < e; n += 16) {      // 4 rows in flight per thread, stride 4
        int i0 = idx_of[n], i1 = idx_of[n + 4], i2 = idx_of[n + 8], i3 = idx_of[n + 12];
        unsigned u0 = *reinterpret_cast<const unsigned*>(hp + (size_t)i0 * 128);
        unsigned u1 = *reinterpret_cast<const unsigned*>(hp + (size_t)i1 * 128);
        unsigned u2 = *reinterpret_cast<const unsigned*>(hp + (size_t)i2 * 128);
        unsigned u3 = *reinterpret_cast<const unsigned*>(hp + (size_t)i3 * 128);
        a0 += (b2f_lo(u0) + b2f_lo(u1)) + (b2f_lo(u2) + b2f_lo(u3));
        a1 += (b2f_hi(u0) + b2f_hi(u1)) + (b2f_hi(u2) + b2f_hi(u3));
    }
    for (; n < e; n += 4) {
        unsigned u = *reinterpret_cast<const unsigned*>(hp + (size_t)idx_of[n] * 128);
        a0 += b2f_lo(u); a1 += b2f_hi(u);
    }
    psum[pl][2 * fp]     = a0;
    psum[pl][2 * fp + 1] = a1;
    __syncthreads();
    if (t < HID) {
        float inv = 1.0f / fmaxf((float)(e - s), 1.0f);
        p[t] = (psum[0][t] + psum[1][t] + psum[2][t] + psum[3][t]) * inv;
    }
    __syncthreads();

    // ---- phase 2: MLP, k-range split across 2 groups ----
    const int tt = t & 255, qq = t >> 8;
    const int k0 = qq * 128;
    float a2 = 0.f;
    for (int k = 0; k < 128; ++k)
        a2 = fmaf(p[k0 + k], Wm1[(k0 + k) * HID + tt], a2);
    psum[qq][tt] = a2;
    __syncthreads();
    if (t < HID)
        red[t] = fmaxf(psum[0][t] + psum[1][t] + bm1[t], 0.f) * Wm2[t];
    __syncthreads();
    for (int o = 128; o > 0; o >>= 1) {
        if (t < o) red[t] += red[t + o];
        __syncthreads();
    }
    if (t == 0) out[g] = red[0] + bm2[0];
}

// ---------------- launch ----------------
extern "C" void kernel_launch(void* const* d_in, const int* in_sizes, int n_in,
                              void* d_out, int out_size, void* d_ws, size_t ws_size,
                              hipStream_t stream) {
    const float* x    = (const float*)d_in[0];
    const int*   ei   = (const int*)d_in[1];
    const int*   batch= (const int*)d_in[2];
    const float* W0   = (const float*)d_in[3];
    const float* b0   = (const float*)d_in[4];
    const float* W1   = (const float*)d_in[5];
    const float* b1   = (const float*)d_in[6];
    const float* W2   = (const float*)d_in[7];
    const float* b2   = (const float*)d_in[8];
    const float* Wm1  = (const float*)d_in[9];
    const float* bm1  = (const float*)d_in[10];
    const float* Wm2  = (const float*)d_in[11];
    const float* bm2  = (const float*)d_in[12];
    float* out = (float*)d_out;

    char* ws = (char*)d_ws;
    size_t off = 0;
    auto alloc = [&](size_t bytes) -> void* {
        void* p = ws + off;
        off += (bytes + 255) & ~(size_t)255;
        return p;
    };
    int*   deg    = (int*)  alloc((size_t)N_NODES * 4);
    int*   bcnt   = (int*)  alloc(64 * 4);
    int*   bcur2  = (int*)  alloc(64 * 4);
    int*   gbar   = (int*)  alloc(64 * 4);     // only [0] used; keeps zeroed region contiguous
    float* dis    = (float*)alloc((size_t)N_NODES * 4);
    int*   row_st = (int*)  alloc((size_t)N_NODES * 4);
    int*   bsum   = (int*)  alloc((size_t)64 * 4);
    int*   seq    = (int*)  alloc((size_t)N_EDGES * 4);
    int4*  perm4  = (int4*) alloc((size_t)NPAD * 16);
    int*   idx_of = (int*)  alloc((size_t)N_NODES * 4);
    int2*  csr    = (int2*) alloc((size_t)N_EDGES * 8);
    unsigned short* x_bf  = (unsigned short*)alloc((size_t)NPAD * F_IN * 2);   // [2][NPAD][64] half-major
    unsigned short* Wt0   = (unsigned short*)alloc((size_t)F_IN * HID * 2);
    unsigned short* Wt1   = (unsigned short*)alloc((size_t)HID * HID * 2);
    unsigned short* Wt2   = (unsigned short*)alloc((size_t)HID * HID * 2);
    unsigned short* bufA  = (unsigned short*)alloc((size_t)NPAD * HID * 2);    // fragment layout
    unsigned short* bufB  = (unsigned short*)alloc((size_t)NPAD * HID * 2);    // [2][NPAD][128] half-major

    const int* src = ei;
    const int* dst = ei + N_EDGES;

    // zero deg + bcnt + bcur2 + gbar (contiguous allocations)
    size_t zlen = (size_t)((char*)gbar - (char*)deg) + 64 * 4;
    hipMemsetAsync(deg, 0, zlen, stream);

    prep_kernel      <<<3765, 256, 0, stream>>>(dst, deg, seq, W0, W1, W2, Wt0, Wt1, Wt2);
    scan_fused_kernel<<<NB_SCAN, 256, 0, stream>>>(deg, dis, bcnt, bsum, bcur2, gbar,
                                                   row_st, perm4, idx_of, N_NODES);
    fillcsr_xconv_kernel<<<3125 + 782, 256, 0, stream>>>(src, dst, dis, idx_of, row_st, seq, csr,
                                                         x, perm4, x_bf);

    const int AGG_B = (N_NODES + 3) / 4;
    const int GEMM_B = NPAD / 128;   // 391

    agg_split<F_IN><<<AGG_B * 2, 256, 0, stream>>>(x_bf, perm4, csr, (uint4*)bufA);
    gemm_frag<F_IN><<<GEMM_B, 256, 0, stream>>>((const uint4*)bufA, Wt0, b0, bufB, 1);

    agg_split<HID><<<AGG_B * 2, 256, 0, stream>>>(bufB, perm4, csr, (uint4*)bufA);
    gemm_frag<HID><<<GEMM_B, 256, 0, stream>>>((const uint4*)bufA, Wt1, b1, bufB, 1);

    agg_split<HID><<<AGG_B * 2, 256, 0, stream>>>(bufB, perm4, csr, (uint4*)bufA);
    gemm_frag<HID><<<GEMM_B, 256, 0, stream>>>((const uint4*)bufA, Wt2, b2, bufB, 1);

    pool_mlp_kernel<<<N_GRAPHS, 512, 0, stream>>>(bufB, batch, idx_of, Wm1, bm1, Wm2, bm2, out);
}

// Round 14
// 390.747 us; speedup vs baseline: 1.0151x; 1.0151x over previous
//
#include <hip/hip_runtime.h>

// ---------------- problem constants ----------------
constexpr int N_NODES  = 50000;
constexpr int N_EDGES  = 800000;
constexpr int N_GRAPHS = 512;
constexpr int F_IN     = 128;
constexpr int HID      = 256;
constexpr int NPAD     = 50048;   // 391*128 padded rows
constexpr int NB_SCAN  = 49;      // scan blocks (1024 nodes each)

typedef short short8 __attribute__((ext_vector_type(8)));
typedef float f32x4  __attribute__((ext_vector_type(4)));

// bf16 helpers (raw ushort storage; RNE rounding)
__device__ __forceinline__ unsigned short f2b(float f) {
    unsigned u = __float_as_uint(f);
    u += 0x7fffu + ((u >> 16) & 1u);
    return (unsigned short)(u >> 16);
}
__device__ __forceinline__ float b2f_lo(unsigned u) { return __uint_as_float(u << 16); }
__device__ __forceinline__ float b2f_hi(unsigned u) { return __uint_as_float(u & 0xffff0000u); }

// ---------------- fused prep: deg histogram (+seq capture) + weights -> B-fragment ----------------
// seq[e] = this edge's per-destination ordinal (free byproduct of the histogram atomic).
// Wt_frag short index: half*(K*128) + ((k>>3)*128 + (n&127))*8 + (k&7), half = n>>7
__global__ __launch_bounds__(256) void prep_kernel(
    const int* __restrict__ dst, int* __restrict__ deg, int* __restrict__ seq,
    const float* __restrict__ W0, const float* __restrict__ W1, const float* __restrict__ W2,
    unsigned short* __restrict__ Wt0, unsigned short* __restrict__ Wt1, unsigned short* __restrict__ Wt2)
{
    const int b = blockIdx.x, t = threadIdx.x;
    if (b < 3125) {
        int e = b * 256 + t;                       // 3125*256 == 800000
        seq[e] = atomicAdd(&deg[dst[e]], 1);
    } else {
        int i = (b - 3125) * 256 + t;              // 640*256 == 163840
        const float* W; unsigned short* Wt; int K; int j;
        if (i < 32768)      { W = W0; Wt = Wt0; K = 128; j = i; }
        else if (i < 98304) { W = W1; Wt = Wt1; K = 256; j = i - 32768; }
        else                { W = W2; Wt = Wt2; K = 256; j = i - 98304; }
        int k = j >> 8, n = j & 255;
        int idx = (n >> 7) * (K * 128) + (((k >> 3) * 128 + (n & 127)) << 3) + (k & 7);
        Wt[idx] = f2b(W[j]);
    }
}

// ---------------- fused scan: 3 kernels -> 1 with a device-scope grid barrier ----------------
// 49 blocks x 1024 nodes. Stage 1: per-block degree sums + dis + bucket hist (publish via
// atomics -> coherent point, safe under XCD non-coherence). Grid barrier (fence + atomic
// arrive + spin; 49 blocks trivially co-resident). Stage 2 (redundant per block): 64-wide
// scans of bsum/bcnt read back via atomics. Stage 3: local node scan -> row_start, perm4
// {node,start,end,dis_bits} sorted by DESC degree, idx_of. bcur2 is a fresh zeroed
// per-bucket cursor (bucket bases derived from the bcnt scan).
__global__ __launch_bounds__(256) void scan_fused_kernel(
    const int* __restrict__ deg, float* __restrict__ dis,
    int* __restrict__ bcnt, int* __restrict__ bsum,
    int* __restrict__ bcur2, int* __restrict__ gbar,
    int* __restrict__ row_start, int4* __restrict__ perm4, int* __restrict__ idx_of, int n)
{
    __shared__ int sm[256];
    __shared__ int h64[64];     // stage1 LDS hist; stage2 bcnt inclusive scan
    __shared__ int horig[64];   // stage2 bcnt originals
    __shared__ int sscan[64];   // stage2 bsum inclusive scan
    __shared__ int lcnt[64], lbase[64];
    const int t = threadIdx.x, b = blockIdx.x, base = b * 1024;
    const int idx0 = base + t * 4;

    // ---- stage 1 ----
    if (t < 64) h64[t] = 0;
    __syncthreads();
    int v[4], s1 = 0;
    #pragma unroll
    for (int i = 0; i < 4; ++i) {
        int id = idx0 + i;
        v[i] = (id < n) ? deg[id] : 0; s1 += v[i];
        if (id < n) {
            dis[id] = rsqrtf((float)v[i] + 1.0f);
            atomicAdd(&h64[63 - min(v[i], 63)], 1);   // bucket 0 = heaviest
        }
    }
    sm[t] = s1; __syncthreads();
    for (int o = 128; o > 0; o >>= 1) { if (t < o) sm[t] += sm[t + o]; __syncthreads(); }
    if (t == 0) atomicExch(&bsum[b], sm[0]);          // coherent publish
    if (t < 64 && h64[t]) atomicAdd(&bcnt[t], h64[t]);

    // ---- grid barrier ----
    __threadfence();
    __syncthreads();
    if (t == 0) {
        atomicAdd(gbar, 1);
        while (atomicAdd(gbar, 0) < (int)gridDim.x) { }
    }
    __syncthreads();
    __threadfence();

    // ---- stage 2: redundant 64-wide scans (reads via atomics -> coherent) ----
    if (t < 64) {
        sscan[t] = (t < NB_SCAN) ? atomicAdd(&bsum[t], 0) : 0;
        int bc = atomicAdd(&bcnt[t], 0);
        horig[t] = bc; h64[t] = bc;
    }
    __syncthreads();
    for (int o = 1; o < 64; o <<= 1) {
        int a = (t >= o && t < 64) ? sscan[t - o] : 0;
        int c = (t >= o && t < 64) ? h64[t - o]  : 0;
        __syncthreads();
        if (t < 64) { sscan[t] += a; h64[t] += c; }
        __syncthreads();
    }
    const int myExcl = (b == 0) ? 0 : sscan[b - 1];   // edge-offset base for this block

    // ---- stage 3: local scans + outputs ----
    if (t < 64) lcnt[t] = 0;
    sm[t] = s1; __syncthreads();
    for (int o = 1; o < 256; o <<= 1) {
        int a = (t >= o) ? sm[t - o] : 0; __syncthreads();
        sm[t] += a; __syncthreads();
    }
    int excl = myExcl + sm[t] - s1;
    int st[4], lp[4];
    #pragma unroll
    for (int i = 0; i < 4; ++i) {
        int id = idx0 + i;
        st[i] = excl;
        if (id < n) {
            row_start[id] = excl;
            lp[i] = atomicAdd(&lcnt[63 - min(v[i], 63)], 1);
        }
        excl += v[i];
    }
    __syncthreads();
    if (t < 64) lbase[t] = lcnt[t] ? (h64[t] - horig[t]) + atomicAdd(&bcur2[t], lcnt[t]) : 0;
    __syncthreads();
    #pragma unroll
    for (int i = 0; i < 4; ++i) {
        int id = idx0 + i;
        if (id < n) {
            int hb = 63 - min(v[i], 63);
            int pos = lbase[hb] + lp[i];
            perm4[pos] = make_int4(id, st[i], st[i] + v[i],
                                   __float_as_int(rsqrtf((float)v[i] + 1.0f)));
            idx_of[id] = pos;
        }
    }
}

// ---------------- merged: CSR scatter (atomic-free via seq) + x -> bf16 half-major ----------------
// pos = row_start[d] + seq[e]: plain L2-resident loads replace the 800k cursor atomics.
__global__ __launch_bounds__(256) void fillcsr_xconv_kernel(
    const int* __restrict__ src, const int* __restrict__ dst,
    const float* __restrict__ dis, const int* __restrict__ idx_of,
    const int* __restrict__ row_start, const int* __restrict__ seq,
    int2* __restrict__ csr,
    const float* __restrict__ x, const int4* __restrict__ perm4,
    unsigned short* __restrict__ x_bf)
{
    const int b = blockIdx.x, t = threadIdx.x;
    if (b < 3125) {
        int e = b * 256 + t;                       // 3125*256 == 800000
        int s = src[e], d = dst[e];
        int pos = row_start[d] + seq[e];
        float w = dis[s] * dis[d];
        csr[pos] = make_int2(idx_of[s], __float_as_int(w));
    } else {
        int idx = (b - 3125) * 64 + (t >> 2);      // 782*64 >= NPAD
        if (idx >= N_NODES) return;
        int node = perm4[idx].x;
        int c = t & 3;                             // 32-feat chunk
        const float4* xs = reinterpret_cast<const float4*>(x + (size_t)node * 128 + c * 32);
        // half-major dest: half = c>>1, offset within half = (c&1)*32
        unsigned short* dp = x_bf + ((size_t)(c >> 1) * NPAD + idx) * 64 + (c & 1) * 32;
        #pragma unroll
        for (int u = 0; u < 8; ++u) {
            float4 v = xs[u];
            unsigned r0 = (unsigned)f2b(v.x) | ((unsigned)f2b(v.y) << 16);
            unsigned r1 = (unsigned)f2b(v.z) | ((unsigned)f2b(v.w) << 16);
            *reinterpret_cast<uint2*>(dp + u * 4) = make_uint2(r0, r1);
        }
    }
}

// ---------------- aggregation, feature-half partitioned (P=2, XCD-parity routed) ----------------
// hin half-major [2][NPAD][F/2] bf16. Half h = blockIdx&1 -> even/odd XCDs; per-XCD L2
// working set = F/2*2B*NPAD (6.4MB @F=128, 12.8MB @F=256).
// NO nontemporal hints anywhere: nt store cost +24MB WRITE (round 8), nt CSR load cost
// -13% gather rate + CSR re-fetch (round 9). Plain loads/stores throughout.
// 16 edges per wave-iter in both instantiations. Fragment-layout output.
template<int F>
__global__ __launch_bounds__(256) void agg_split(
    const unsigned short* __restrict__ hin, const int4* __restrict__ perm4,
    const int2* __restrict__ csr, uint4* __restrict__ out4)
{
    constexpr int ROW  = F / 2;       // feats per half-row: 128 / 64
    constexpr int LPR  = ROW / 8;     // lanes per half-row: 16 / 8
    constexpr int NSUB = 64 / LPR;    // subgroups per wave: 4 / 8
    constexpr int EPS  = 16 / NSUB;   // edges per subgroup per main iter: 4 / 2
    const int gid  = blockIdx.x;
    const int hh   = gid & 1;         // feature half, matches XCD parity
    const int nb   = gid >> 1;
    const int lane = threadIdx.x & 63;
    const int sub  = lane / LPR;
    const int fcl  = lane % LPR;      // 16B chunk within half
    const int idx  = nb * 4 + (threadIdx.x >> 6);
    if (idx >= N_NODES) return;
    const int4 p = perm4[idx];
    const float dn = __int_as_float(p.w);
    const unsigned short* hb = hin + (size_t)hh * NPAD * ROW;

    float acc[8];
    {   // self-loop term (sub 0 only covers the full half-row)
        float sw = (sub == 0) ? dn * dn : 0.0f;
        uint2 u2[2];
        *reinterpret_cast<uint4*>(u2) =
            *reinterpret_cast<const uint4*>(hb + (size_t)idx * ROW + fcl * 8);
        #pragma unroll
        for (int h = 0; h < 2; ++h) {
            acc[h * 4 + 0] = b2f_lo(u2[h].x) * sw;
            acc[h * 4 + 1] = b2f_hi(u2[h].x) * sw;
            acc[h * 4 + 2] = b2f_lo(u2[h].y) * sw;
            acc[h * 4 + 3] = b2f_hi(u2[h].y) * sw;
        }
    }

    int j = p.y;
    const int end = p.z;
    for (; j + 16 <= end; j += 16) {
        int2 c[EPS];
        uint2 g[EPS][2];
        #pragma unroll
        for (int u = 0; u < EPS; ++u) c[u] = csr[j + sub * EPS + u];
        #pragma unroll
        for (int u = 0; u < EPS; ++u)
            *reinterpret_cast<uint4*>(g[u]) =
                *reinterpret_cast<const uint4*>(hb + (size_t)c[u].x * ROW + fcl * 8);
        #pragma unroll
        for (int u = 0; u < EPS; ++u) {
            float w = __int_as_float(c[u].y);
            #pragma unroll
            for (int h = 0; h < 2; ++h) {
                acc[h * 4 + 0] = fmaf(b2f_lo(g[u][h].x), w, acc[h * 4 + 0]);
                acc[h * 4 + 1] = fmaf(b2f_hi(g[u][h].x), w, acc[h * 4 + 1]);
                acc[h * 4 + 2] = fmaf(b2f_lo(g[u][h].y), w, acc[h * 4 + 2]);
                acc[h * 4 + 3] = fmaf(b2f_hi(g[u][h].y), w, acc[h * 4 + 3]);
            }
        }
    }
    int jj = j + sub;
    for (; jj + NSUB < end; jj += 2 * NSUB) {
        int2 c0 = csr[jj], c1 = csr[jj + NSUB];
        uint2 g0[2], g1[2];
        *reinterpret_cast<uint4*>(g0) =
            *reinterpret_cast<const uint4*>(hb + (size_t)c0.x * ROW + fcl * 8);
        *reinterpret_cast<uint4*>(g1) =
            *reinterpret_cast<const uint4*>(hb + (size_t)c1.x * ROW + fcl * 8);
        float w0 = __int_as_float(c0.y), w1 = __int_as_float(c1.y);
        #pragma unroll
        for (int h = 0; h < 2; ++h) {
            acc[h * 4 + 0] = fmaf(b2f_lo(g0[h].x), w0, fmaf(b2f_lo(g1[h].x), w1, acc[h * 4 + 0]));
            acc[h * 4 + 1] = fmaf(b2f_hi(g0[h].x), w0, fmaf(b2f_hi(g1[h].x), w1, acc[h * 4 + 1]));
            acc[h * 4 + 2] = fmaf(b2f_lo(g0[h].y), w0, fmaf(b2f_lo(g1[h].y), w1, acc[h * 4 + 2]));
            acc[h * 4 + 3] = fmaf(b2f_hi(g0[h].y), w0, fmaf(b2f_hi(g1[h].y), w1, acc[h * 4 + 3]));
        }
    }
    if (jj < end) {
        int2 c0 = csr[jj];
        float w = __int_as_float(c0.y);
        uint2 g[2];
        *reinterpret_cast<uint4*>(g) =
            *reinterpret_cast<const uint4*>(hb + (size_t)c0.x * ROW + fcl * 8);
        #pragma unroll
        for (int h = 0; h < 2; ++h) {
            acc[h * 4 + 0] = fmaf(b2f_lo(g[h].x), w, acc[h * 4 + 0]);
            acc[h * 4 + 1] = fmaf(b2f_hi(g[h].x), w, acc[h * 4 + 1]);
            acc[h * 4 + 2] = fmaf(b2f_lo(g[h].y), w, acc[h * 4 + 2]);
            acc[h * 4 + 3] = fmaf(b2f_hi(g[h].y), w, acc[h * 4 + 3]);
        }
    }

    #pragma unroll
    for (int k = 0; k < 8; ++k) {
        #pragma unroll
        for (int off = LPR; off < 64; off <<= 1)
            acc[k] += __shfl_xor(acc[k], off, 64);
    }

    if (sub == 0) {
        uint2 r[2];
        #pragma unroll
        for (int h = 0; h < 2; ++h) {
            r[h].x = (unsigned)f2b(acc[h * 4 + 0]) | ((unsigned)f2b(acc[h * 4 + 1]) << 16);
            r[h].y = (unsigned)f2b(acc[h * 4 + 2]) | ((unsigned)f2b(acc[h * 4 + 3]) << 16);
        }
        int fc = hh * LPR + fcl;                   // global 16B chunk (0..F/8)
        int chunk = (idx >> 7) * (128 * (F / 8)) + fc * 128 + (idx & 127);
        out4[chunk] = *reinterpret_cast<uint4*>(r);
    }
}

// ---------------- MFMA GEMM, fragment-direct A, one weight-half resident in LDS ----------------
// A in fragment layout [panel][kchunk][row][8]; Wt_frag in [half][kchunk][col][8].
// C output HALF-MAJOR [2][NPAD][128] bf16 (permuted rows). grid (NPAD/128, 2); 4 waves.
// (Round-13 lesson: merging both halves into one 128KB-LDS block drops to 1 block/CU
//  with a 47%-idle second dispatch wave: +11 us. 64KB/2-half shape is optimal here.)
template<int K>
__global__ __launch_bounds__(256) void gemm_frag(
    const uint4* __restrict__ A4,
    const unsigned short* __restrict__ Wt_frag,
    const float* __restrict__ bias,
    unsigned short* __restrict__ C,
    int relu)
{
    __shared__ __align__(16) unsigned short Bs[K * 128];   // 64 KB (K=256) / 32 KB (K=128)
    const int t    = threadIdx.x;
    const int lane = t & 63;
    const int w    = t >> 6;
    const int wm   = w & 1, wn = w >> 1;
    const int q    = lane >> 4, m = lane & 15;
    const int panel = blockIdx.x;
    const int col0  = blockIdx.y * 128;

    {
        const uint4* src4 = reinterpret_cast<const uint4*>(Wt_frag + blockIdx.y * (K * 128));
        uint4* dst4 = reinterpret_cast<uint4*>(Bs);
        #pragma unroll
        for (int it = 0; it < K / 16; ++it)
            dst4[it * 256 + t] = src4[it * 256 + t];
    }
    __syncthreads();

    f32x4 acc[4][4] = {};
    const int abase = panel * (128 * (K / 8));

    #pragma unroll
    for (int kb = 0; kb < K / 32; ++kb) {
        short8 af[4], bf[4];
        #pragma unroll
        for (int i = 0; i < 4; ++i) {
            uint4 v = A4[abase + (kb * 4 + q) * 128 + wm * 64 + i * 16 + m];
            af[i] = *reinterpret_cast<short8*>(&v);
        }
        #pragma unroll
        for (int jn = 0; jn < 4; ++jn)
            bf[jn] = *reinterpret_cast<const short8*>(&Bs[((kb * 4 + q) * 128 + wn * 64 + jn * 16 + m) * 8]);
        #pragma unroll
        for (int i = 0; i < 4; ++i)
            #pragma unroll
            for (int jn = 0; jn < 4; ++jn)
                acc[i][jn] = __builtin_amdgcn_mfma_f32_16x16x32_bf16(af[i], bf[jn], acc[i][jn], 0, 0, 0);
    }

    // epilogue: C/D layout col = lane&15, row = (lane>>4)*4 + reg; half-major bf16 out
    #pragma unroll
    for (int jn = 0; jn < 4; ++jn) {
        int col = col0 + wn * 64 + jn * 16 + m;
        float bj = bias[col];
        int ch = col >> 7, cc = col & 127;
        #pragma unroll
        for (int i = 0; i < 4; ++i) {
            int rowb = panel * 128 + wm * 64 + i * 16 + q * 4;
            #pragma unroll
            for (int r = 0; r < 4; ++r) {
                float v = acc[i][jn][r] + bj;
                if (relu) v = fmaxf(v, 0.f);
                C[((size_t)ch * NPAD + (rowb + r)) * 128 + cc] = f2b(v);
            }
        }
    }
}

// ---------------- fused pool + MLP head: 512 threads ----------------
// Phase 1 (pooling): threads = 128 feature-pairs x 4 node-lanes; uint loads (2 bf16),
// 4 rows in flight per thread -> 16 rows/iter per block. Phase 2 (MLP): 256 feats x
// 2 k-halves (128 iters each). LDS mediates the phase remap.
__global__ __launch_bounds__(512) void pool_mlp_kernel(
    const unsigned short* __restrict__ h, const int* __restrict__ batch,
    const int* __restrict__ idx_of,
    const float* __restrict__ Wm1, const float* __restrict__ bm1,
    const float* __restrict__ Wm2, const float* __restrict__ bm2,
    float* __restrict__ out)
{
    __shared__ float psum[4][HID];     // phase1 partials; reused as [2][HID] in phase2
    __shared__ float p[HID];
    __shared__ float red[HID];
    __shared__ int se[2];
    const int g = blockIdx.x, t = threadIdx.x;
    if (t < 2) {
        int target = g + t;
        int lo = 0, hi = N_NODES;
        while (lo < hi) { int mid = (lo + hi) >> 1; if (batch[mid] < target) lo = mid + 1; else hi = mid; }
        se[t] = lo;
    }
    __syncthreads();
    const int s = se[0], e = se[1];

    // ---- phase 1: pooled sums ----
    const int fp = t & 127;            // feature pair: feats 2fp, 2fp+1
    const int pl = t >> 7;             // node lane 0..3
    const unsigned short* hp = h + (size_t)(fp >> 6) * ((size_t)NPAD * 128) + ((2 * fp) & 127);
    float a0 = 0.f, a1 = 0.f;
    int n = s + pl;
    for (; n + 12 < e; n += 16) {      // 4 rows in flight per thread, stride 4
        int i0 = idx_of[n], i1 = idx_of[n + 4], i2 = idx_of[n + 8], i3 = idx_of[n + 12];
        unsigned u0 = *reinterpret_cast<const unsigned*>(hp + (size_t)i0 * 128);
        unsigned u1 = *reinterpret_cast<const unsigned*>(hp + (size_t)i1 * 128);
        unsigned u2 = *reinterpret_cast<const unsigned*>(hp + (size_t)i2 * 128);
        unsigned u3 = *reinterpret_cast<const unsigned*>(hp + (size_t)i3 * 128);
        a0 += (b2f_lo(u0) + b2f_lo(u1)) + (b2f_lo(u2) + b2f_lo(u3));
        a1 += (b2f_hi(u0) + b2f_hi(u1)) + (b2f_hi(u2) + b2f_hi(u3));
    }
    for (; n < e; n += 4) {
        unsigned u = *reinterpret_cast<const unsigned*>(hp + (size_t)idx_of[n] * 128);
        a0 += b2f_lo(u); a1 += b2f_hi(u);
    }
    psum[pl][2 * fp]     = a0;
    psum[pl][2 * fp + 1] = a1;
    __syncthreads();
    if (t < HID) {
        float inv = 1.0f / fmaxf((float)(e - s), 1.0f);
        p[t] = (psum[0][t] + psum[1][t] + psum[2][t] + psum[3][t]) * inv;
    }
    __syncthreads();

    // ---- phase 2: MLP, k-range split across 2 groups ----
    const int tt = t & 255, qq = t >> 8;
    const int k0 = qq * 128;
    float a2 = 0.f;
    for (int k = 0; k < 128; ++k)
        a2 = fmaf(p[k0 + k], Wm1[(k0 + k) * HID + tt], a2);
    psum[qq][tt] = a2;
    __syncthreads();
    if (t < HID)
        red[t] = fmaxf(psum[0][t] + psum[1][t] + bm1[t], 0.f) * Wm2[t];
    __syncthreads();
    for (int o = 128; o > 0; o >>= 1) {
        if (t < o) red[t] += red[t + o];
        __syncthreads();
    }
    if (t == 0) out[g] = red[0] + bm2[0];
}

// ---------------- launch ----------------
extern "C" void kernel_launch(void* const* d_in, const int* in_sizes, int n_in,
                              void* d_out, int out_size, void* d_ws, size_t ws_size,
                              hipStream_t stream) {
    const float* x    = (const float*)d_in[0];
    const int*   ei   = (const int*)d_in[1];
    const int*   batch= (const int*)d_in[2];
    const float* W0   = (const float*)d_in[3];
    const float* b0   = (const float*)d_in[4];
    const float* W1   = (const float*)d_in[5];
    const float* b1   = (const float*)d_in[6];
    const float* W2   = (const float*)d_in[7];
    const float* b2   = (const float*)d_in[8];
    const float* Wm1  = (const float*)d_in[9];
    const float* bm1  = (const float*)d_in[10];
    const float* Wm2  = (const float*)d_in[11];
    const float* bm2  = (const float*)d_in[12];
    float* out = (float*)d_out;

    char* ws = (char*)d_ws;
    size_t off = 0;
    auto alloc = [&](size_t bytes) -> void* {
        void* p = ws + off;
        off += (bytes + 255) & ~(size_t)255;
        return p;
    };
    int*   deg    = (int*)  alloc((size_t)N_NODES * 4);
    int*   bcnt   = (int*)  alloc(64 * 4);
    int*   bcur2  = (int*)  alloc(64 * 4);
    int*   gbar   = (int*)  alloc(64 * 4);     // only [0] used; keeps zeroed region contiguous
    float* dis    = (float*)alloc((size_t)N_NODES * 4);
    int*   row_st = (int*)  alloc((size_t)N_NODES * 4);
    int*   bsum   = (int*)  alloc((size_t)64 * 4);
    int*   seq    = (int*)  alloc((size_t)N_EDGES * 4);
    int4*  perm4  = (int4*) alloc((size_t)NPAD * 16);
    int*   idx_of = (int*)  alloc((size_t)N_NODES * 4);
    int2*  csr    = (int2*) alloc((size_t)N_EDGES * 8);
    unsigned short* x_bf  = (unsigned short*)alloc((size_t)NPAD * F_IN * 2);   // [2][NPAD][64] half-major
    unsigned short* Wt0   = (unsigned short*)alloc((size_t)F_IN * HID * 2);
    unsigned short* Wt1   = (unsigned short*)alloc((size_t)HID * HID * 2);
    unsigned short* Wt2   = (unsigned short*)alloc((size_t)HID * HID * 2);
    unsigned short* bufA  = (unsigned short*)alloc((size_t)NPAD * HID * 2);    // fragment layout
    unsigned short* bufB  = (unsigned short*)alloc((size_t)NPAD * HID * 2);    // [2][NPAD][128] half-major

    const int* src = ei;
    const int* dst = ei + N_EDGES;

    // zero deg + bcnt + bcur2 + gbar (contiguous allocations)
    size_t zlen = (size_t)((char*)gbar - (char*)deg) + 64 * 4;
    hipMemsetAsync(deg, 0, zlen, stream);

    prep_kernel      <<<3765, 256, 0, stream>>>(dst, deg, seq, W0, W1, W2, Wt0, Wt1, Wt2);
    scan_fused_kernel<<<NB_SCAN, 256, 0, stream>>>(deg, dis, bcnt, bsum, bcur2, gbar,
                                                   row_st, perm4, idx_of, N_NODES);
    fillcsr_xconv_kernel<<<3125 + 782, 256, 0, stream>>>(src, dst, dis, idx_of, row_st, seq, csr,
                                                         x, perm4, x_bf);

    dim3 ggrid(NPAD / 128, 2);
    const int AGG_B = (N_NODES + 3) / 4;

    agg_split<F_IN><<<AGG_B * 2, 256, 0, stream>>>(x_bf, perm4, csr, (uint4*)bufA);
    gemm_frag<F_IN><<<ggrid, 256, 0, stream>>>((const uint4*)bufA, Wt0, b0, bufB, 1);

    agg_split<HID><<<AGG_B * 2, 256, 0, stream>>>(bufB, perm4, csr, (uint4*)bufA);
    gemm_frag<HID><<<ggrid, 256, 0, stream>>>((const uint4*)bufA, Wt1, b1, bufB, 1);

    agg_split<HID><<<AGG_B * 2, 256, 0, stream>>>(bufB, perm4, csr, (uint4*)bufA);
    gemm_frag<HID><<<ggrid, 256, 0, stream>>>((const uint4*)bufA, Wt2, b2, bufB, 1);

    pool_mlp_kernel<<<N_GRAPHS, 512, 0, stream>>>(bufB, batch, idx_of, Wm1, bm1, Wm2, bm2, out);
}

// Round 15
// 383.751 us; speedup vs baseline: 1.0336x; 1.0182x over previous
//
#include <hip/hip_runtime.h>

// ---------------- problem constants ----------------
constexpr int N_NODES  = 50000;
constexpr int N_EDGES  = 800000;
constexpr int N_GRAPHS = 512;
constexpr int F_IN     = 128;
constexpr int HID      = 256;
constexpr int NPAD     = 50048;   // 391*128 padded rows

typedef short short8 __attribute__((ext_vector_type(8)));
typedef float f32x4  __attribute__((ext_vector_type(4)));

// bf16 helpers (raw ushort storage; RNE rounding)
__device__ __forceinline__ unsigned short f2b(float f) {
    unsigned u = __float_as_uint(f);
    u += 0x7fffu + ((u >> 16) & 1u);
    return (unsigned short)(u >> 16);
}
__device__ __forceinline__ float b2f_lo(unsigned u) { return __uint_as_float(u << 16); }
__device__ __forceinline__ float b2f_hi(unsigned u) { return __uint_as_float(u & 0xffff0000u); }

// ---------------- fused prep: deg histogram (+seq capture) + weights -> B-fragment ----------------
// seq[e] = this edge's per-destination ordinal (free byproduct of the histogram atomic).
// Wt_frag short index: half*(K*128) + ((k>>3)*128 + (n&127))*8 + (k&7), half = n>>7
__global__ __launch_bounds__(256) void prep_kernel(
    const int* __restrict__ dst, int* __restrict__ deg, int* __restrict__ seq,
    const float* __restrict__ W0, const float* __restrict__ W1, const float* __restrict__ W2,
    unsigned short* __restrict__ Wt0, unsigned short* __restrict__ Wt1, unsigned short* __restrict__ Wt2)
{
    const int b = blockIdx.x, t = threadIdx.x;
    if (b < 3125) {
        int e = b * 256 + t;                       // 3125*256 == 800000
        seq[e] = atomicAdd(&deg[dst[e]], 1);
    } else {
        int i = (b - 3125) * 256 + t;              // 640*256 == 163840
        const float* W; unsigned short* Wt; int K; int j;
        if (i < 32768)      { W = W0; Wt = Wt0; K = 128; j = i; }
        else if (i < 98304) { W = W1; Wt = Wt1; K = 256; j = i - 32768; }
        else                { W = W2; Wt = Wt2; K = 256; j = i - 98304; }
        int k = j >> 8, n = j & 255;
        int idx = (n >> 7) * (K * 128) + (((k >> 3) * 128 + (n & 127)) << 3) + (k & 7);
        Wt[idx] = f2b(W[j]);
    }
}

// ---------------- scans (3 kernels), degree-bucket (DESCENDING degree) fused in ----------------
// (Round-13/14 lesson: fusing these behind a device-scope spin barrier costs ~5us --
//  the coherent-line spin + redundant stage-2 scans exceed two graph-captured launches.)
__global__ void block_sum_dis_kernel(const int* __restrict__ deg, int* __restrict__ bsum,
                                     float* __restrict__ dis, int* __restrict__ bcnt, int n) {
    __shared__ int sm[256];
    __shared__ int hist[64];
    int t = threadIdx.x, base = blockIdx.x * 1024;
    if (t < 64) hist[t] = 0;
    __syncthreads();
    int s = 0;
    #pragma unroll
    for (int i = 0; i < 4; ++i) {
        int idx = base + t + i * 256;
        if (idx < n) {
            int d = deg[idx]; s += d;
            dis[idx] = rsqrtf((float)d + 1.0f);
            atomicAdd(&hist[63 - min(d, 63)], 1);   // bucket 0 = heaviest
        }
    }
    sm[t] = s; __syncthreads();
    for (int o = 128; o > 0; o >>= 1) { if (t < o) sm[t] += sm[t + o]; __syncthreads(); }
    if (t == 0) bsum[blockIdx.x] = sm[0];
    if (t < 64 && hist[t]) atomicAdd(&bcnt[t], hist[t]);
}

__global__ void scan_bsum_kernel(int* __restrict__ bsum, int nb,
                                 const int* __restrict__ bcnt, int* __restrict__ bcur) {
    __shared__ int sm[64], sb[64];
    int t = threadIdx.x;
    int v = (t < nb) ? bsum[t] : 0;
    int c = bcnt[t];
    sm[t] = v; sb[t] = c; __syncthreads();
    for (int o = 1; o < 64; o <<= 1) {
        int a = (t >= o) ? sm[t - o] : 0;
        int bb = (t >= o) ? sb[t - o] : 0;
        __syncthreads();
        sm[t] += a; sb[t] += bb;
        __syncthreads();
    }
    if (t < nb) bsum[t] = sm[t] - v;   // exclusive edge-offset scan
    bcur[t] = sb[t] - c;               // exclusive bucket-base scan
}

// builds: row_start (original-id edge offsets), perm4 {node,start,end,dis_bits} sorted
// by DESC degree, idx_of
__global__ void scan_local_kernel(const int* __restrict__ deg, const int* __restrict__ bsum,
                                  int* __restrict__ row_start, int* __restrict__ bcur,
                                  int4* __restrict__ perm4, int* __restrict__ idx_of,
                                  const float* __restrict__ dis, int n) {
    __shared__ int sm[256];
    __shared__ int lcnt[64], lbase[64];
    int t = threadIdx.x, base = blockIdx.x * 1024;
    if (t < 64) lcnt[t] = 0;
    int idx0 = base + t * 4;
    int v[4], s = 0;
    #pragma unroll
    for (int i = 0; i < 4; ++i) { int id = idx0 + i; v[i] = (id < n) ? deg[id] : 0; s += v[i]; }
    sm[t] = s; __syncthreads();
    for (int o = 1; o < 256; o <<= 1) {
        int a = (t >= o) ? sm[t - o] : 0; __syncthreads();
        sm[t] += a; __syncthreads();
    }
    int excl = bsum[blockIdx.x] + sm[t] - s;
    int st[4], lp[4];
    #pragma unroll
    for (int i = 0; i < 4; ++i) {
        int id = idx0 + i;
        st[i] = excl;
        if (id < n) {
            row_start[id] = excl;
            lp[i] = atomicAdd(&lcnt[63 - min(v[i], 63)], 1);
        }
        excl += v[i];
    }
    __syncthreads();
    if (t < 64) lbase[t] = lcnt[t] ? atomicAdd(&bcur[t], lcnt[t]) : 0;
    __syncthreads();
    #pragma unroll
    for (int i = 0; i < 4; ++i) {
        int id = idx0 + i;
        if (id < n) {
            int hb = 63 - min(v[i], 63);
            int pos = lbase[hb] + lp[i];
            perm4[pos] = make_int4(id, st[i], st[i] + v[i], __float_as_int(dis[id]));
            idx_of[id] = pos;
        }
    }
}

// ---------------- merged: CSR scatter (atomic-free via seq) + x -> bf16 half-major ----------------
// pos = row_start[d] + seq[e]: plain L2-resident loads replace the 800k cursor atomics.
__global__ __launch_bounds__(256) void fillcsr_xconv_kernel(
    const int* __restrict__ src, const int* __restrict__ dst,
    const float* __restrict__ dis, const int* __restrict__ idx_of,
    const int* __restrict__ row_start, const int* __restrict__ seq,
    int2* __restrict__ csr,
    const float* __restrict__ x, const int4* __restrict__ perm4,
    unsigned short* __restrict__ x_bf)
{
    const int b = blockIdx.x, t = threadIdx.x;
    if (b < 3125) {
        int e = b * 256 + t;                       // 3125*256 == 800000
        int s = src[e], d = dst[e];
        int pos = row_start[d] + seq[e];
        float w = dis[s] * dis[d];
        csr[pos] = make_int2(idx_of[s], __float_as_int(w));
    } else {
        int idx = (b - 3125) * 64 + (t >> 2);      // 782*64 >= NPAD
        if (idx >= N_NODES) return;
        int node = perm4[idx].x;
        int c = t & 3;                             // 32-feat chunk
        const float4* xs = reinterpret_cast<const float4*>(x + (size_t)node * 128 + c * 32);
        // half-major dest: half = c>>1, offset within half = (c&1)*32
        unsigned short* dp = x_bf + ((size_t)(c >> 1) * NPAD + idx) * 64 + (c & 1) * 32;
        #pragma unroll
        for (int u = 0; u < 8; ++u) {
            float4 v = xs[u];
            unsigned r0 = (unsigned)f2b(v.x) | ((unsigned)f2b(v.y) << 16);
            unsigned r1 = (unsigned)f2b(v.z) | ((unsigned)f2b(v.w) << 16);
            *reinterpret_cast<uint2*>(dp + u * 4) = make_uint2(r0, r1);
        }
    }
}

// ---------------- aggregation, feature-half partitioned (P=2, XCD-parity routed) ----------------
// hin half-major [2][NPAD][F/2] bf16. Half h = blockIdx&1 -> even/odd XCDs; per-XCD L2
// working set = F/2*2B*NPAD (6.4MB @F=128, 12.8MB @F=256).
// NO nontemporal hints anywhere: nt store cost +24MB WRITE (round 8), nt CSR load cost
// -13% gather rate + CSR re-fetch (round 9). Plain loads/stores throughout.
// 16 edges per wave-iter in both instantiations. Fragment-layout output.
template<int F>
__global__ __launch_bounds__(256) void agg_split(
    const unsigned short* __restrict__ hin, const int4* __restrict__ perm4,
    const int2* __restrict__ csr, uint4* __restrict__ out4)
{
    constexpr int ROW  = F / 2;       // feats per half-row: 128 / 64
    constexpr int LPR  = ROW / 8;     // lanes per half-row: 16 / 8
    constexpr int NSUB = 64 / LPR;    // subgroups per wave: 4 / 8
    constexpr int EPS  = 16 / NSUB;   // edges per subgroup per main iter: 4 / 2
    const int gid  = blockIdx.x;
    const int hh   = gid & 1;         // feature half, matches XCD parity
    const int nb   = gid >> 1;
    const int lane = threadIdx.x & 63;
    const int sub  = lane / LPR;
    const int fcl  = lane % LPR;      // 16B chunk within half
    const int idx  = nb * 4 + (threadIdx.x >> 6);
    if (idx >= N_NODES) return;
    const int4 p = perm4[idx];
    const float dn = __int_as_float(p.w);
    const unsigned short* hb = hin + (size_t)hh * NPAD * ROW;

    float acc[8];
    {   // self-loop term (sub 0 only covers the full half-row)
        float sw = (sub == 0) ? dn * dn : 0.0f;
        uint2 u2[2];
        *reinterpret_cast<uint4*>(u2) =
            *reinterpret_cast<const uint4*>(hb + (size_t)idx * ROW + fcl * 8);
        #pragma unroll
        for (int h = 0; h < 2; ++h) {
            acc[h * 4 + 0] = b2f_lo(u2[h].x) * sw;
            acc[h * 4 + 1] = b2f_hi(u2[h].x) * sw;
            acc[h * 4 + 2] = b2f_lo(u2[h].y) * sw;
            acc[h * 4 + 3] = b2f_hi(u2[h].y) * sw;
        }
    }

    int j = p.y;
    const int end = p.z;
    for (; j + 16 <= end; j += 16) {
        int2 c[EPS];
        uint2 g[EPS][2];
        #pragma unroll
        for (int u = 0; u < EPS; ++u) c[u] = csr[j + sub * EPS + u];
        #pragma unroll
        for (int u = 0; u < EPS; ++u)
            *reinterpret_cast<uint4*>(g[u]) =
                *reinterpret_cast<const uint4*>(hb + (size_t)c[u].x * ROW + fcl * 8);
        #pragma unroll
        for (int u = 0; u < EPS; ++u) {
            float w = __int_as_float(c[u].y);
            #pragma unroll
            for (int h = 0; h < 2; ++h) {
                acc[h * 4 + 0] = fmaf(b2f_lo(g[u][h].x), w, acc[h * 4 + 0]);
                acc[h * 4 + 1] = fmaf(b2f_hi(g[u][h].x), w, acc[h * 4 + 1]);
                acc[h * 4 + 2] = fmaf(b2f_lo(g[u][h].y), w, acc[h * 4 + 2]);
                acc[h * 4 + 3] = fmaf(b2f_hi(g[u][h].y), w, acc[h * 4 + 3]);
            }
        }
    }
    int jj = j + sub;
    for (; jj + NSUB < end; jj += 2 * NSUB) {
        int2 c0 = csr[jj], c1 = csr[jj + NSUB];
        uint2 g0[2], g1[2];
        *reinterpret_cast<uint4*>(g0) =
            *reinterpret_cast<const uint4*>(hb + (size_t)c0.x * ROW + fcl * 8);
        *reinterpret_cast<uint4*>(g1) =
            *reinterpret_cast<const uint4*>(hb + (size_t)c1.x * ROW + fcl * 8);
        float w0 = __int_as_float(c0.y), w1 = __int_as_float(c1.y);
        #pragma unroll
        for (int h = 0; h < 2; ++h) {
            acc[h * 4 + 0] = fmaf(b2f_lo(g0[h].x), w0, fmaf(b2f_lo(g1[h].x), w1, acc[h * 4 + 0]));
            acc[h * 4 + 1] = fmaf(b2f_hi(g0[h].x), w0, fmaf(b2f_hi(g1[h].x), w1, acc[h * 4 + 1]));
            acc[h * 4 + 2] = fmaf(b2f_lo(g0[h].y), w0, fmaf(b2f_lo(g1[h].y), w1, acc[h * 4 + 2]));
            acc[h * 4 + 3] = fmaf(b2f_hi(g0[h].y), w0, fmaf(b2f_hi(g1[h].y), w1, acc[h * 4 + 3]));
        }
    }
    if (jj < end) {
        int2 c0 = csr[jj];
        float w = __int_as_float(c0.y);
        uint2 g[2];
        *reinterpret_cast<uint4*>(g) =
            *reinterpret_cast<const uint4*>(hb + (size_t)c0.x * ROW + fcl * 8);
        #pragma unroll
        for (int h = 0; h < 2; ++h) {
            acc[h * 4 + 0] = fmaf(b2f_lo(g[h].x), w, acc[h * 4 + 0]);
            acc[h * 4 + 1] = fmaf(b2f_hi(g[h].x), w, acc[h * 4 + 1]);
            acc[h * 4 + 2] = fmaf(b2f_lo(g[h].y), w, acc[h * 4 + 2]);
            acc[h * 4 + 3] = fmaf(b2f_hi(g[h].y), w, acc[h * 4 + 3]);
        }
    }

    #pragma unroll
    for (int k = 0; k < 8; ++k) {
        #pragma unroll
        for (int off = LPR; off < 64; off <<= 1)
            acc[k] += __shfl_xor(acc[k], off, 64);
    }

    if (sub == 0) {
        uint2 r[2];
        #pragma unroll
        for (int h = 0; h < 2; ++h) {
            r[h].x = (unsigned)f2b(acc[h * 4 + 0]) | ((unsigned)f2b(acc[h * 4 + 1]) << 16);
            r[h].y = (unsigned)f2b(acc[h * 4 + 2]) | ((unsigned)f2b(acc[h * 4 + 3]) << 16);
        }
        int fc = hh * LPR + fcl;                   // global 16B chunk (0..F/8)
        int chunk = (idx >> 7) * (128 * (F / 8)) + fc * 128 + (idx & 127);
        out4[chunk] = *reinterpret_cast<uint4*>(r);
    }
}

// ---------------- MFMA GEMM, fragment-direct A, one weight-half resident in LDS ----------------
// A in fragment layout [panel][kchunk][row][8]; Wt_frag in [half][kchunk][col][8].
// C output HALF-MAJOR [2][NPAD][128] bf16 (permuted rows). grid (NPAD/128, 2); 4 waves.
// (Round-13 lesson: merging both halves into one 128KB-LDS block drops to 1 block/CU
//  with a 47%-idle second dispatch wave: +11 us. 64KB/2-half shape is optimal here.)
template<int K>
__global__ __launch_bounds__(256) void gemm_frag(
    const uint4* __restrict__ A4,
    const unsigned short* __restrict__ Wt_frag,
    const float* __restrict__ bias,
    unsigned short* __restrict__ C,
    int relu)
{
    __shared__ __align__(16) unsigned short Bs[K * 128];   // 64 KB (K=256) / 32 KB (K=128)
    const int t    = threadIdx.x;
    const int lane = t & 63;
    const int w    = t >> 6;
    const int wm   = w & 1, wn = w >> 1;
    const int q    = lane >> 4, m = lane & 15;
    const int panel = blockIdx.x;
    const int col0  = blockIdx.y * 128;

    {
        const uint4* src4 = reinterpret_cast<const uint4*>(Wt_frag + blockIdx.y * (K * 128));
        uint4* dst4 = reinterpret_cast<uint4*>(Bs);
        #pragma unroll
        for (int it = 0; it < K / 16; ++it)
            dst4[it * 256 + t] = src4[it * 256 + t];
    }
    __syncthreads();

    f32x4 acc[4][4] = {};
    const int abase = panel * (128 * (K / 8));

    #pragma unroll
    for (int kb = 0; kb < K / 32; ++kb) {
        short8 af[4], bf[4];
        #pragma unroll
        for (int i = 0; i < 4; ++i) {
            uint4 v = A4[abase + (kb * 4 + q) * 128 + wm * 64 + i * 16 + m];
            af[i] = *reinterpret_cast<short8*>(&v);
        }
        #pragma unroll
        for (int jn = 0; jn < 4; ++jn)
            bf[jn] = *reinterpret_cast<const short8*>(&Bs[((kb * 4 + q) * 128 + wn * 64 + jn * 16 + m) * 8]);
        #pragma unroll
        for (int i = 0; i < 4; ++i)
            #pragma unroll
            for (int jn = 0; jn < 4; ++jn)
                acc[i][jn] = __builtin_amdgcn_mfma_f32_16x16x32_bf16(af[i], bf[jn], acc[i][jn], 0, 0, 0);
    }

    // epilogue: C/D layout col = lane&15, row = (lane>>4)*4 + reg; half-major bf16 out
    #pragma unroll
    for (int jn = 0; jn < 4; ++jn) {
        int col = col0 + wn * 64 + jn * 16 + m;
        float bj = bias[col];
        int ch = col >> 7, cc = col & 127;
        #pragma unroll
        for (int i = 0; i < 4; ++i) {
            int rowb = panel * 128 + wm * 64 + i * 16 + q * 4;
            #pragma unroll
            for (int r = 0; r < 4; ++r) {
                float v = acc[i][jn][r] + bj;
                if (relu) v = fmaxf(v, 0.f);
                C[((size_t)ch * NPAD + (rowb + r)) * 128 + cc] = f2b(v);
            }
        }
    }
}

// ---------------- fused pool + MLP head: 512 threads ----------------
// Phase 1 (pooling): threads = 128 feature-pairs x 4 node-lanes; uint loads (2 bf16),
// 4 rows in flight per thread -> 16 rows/iter per block. Phase 2 (MLP): 256 feats x
// 2 k-halves (128 iters each). LDS mediates the phase remap.
__global__ __launch_bounds__(512) void pool_mlp_kernel(
    const unsigned short* __restrict__ h, const int* __restrict__ batch,
    const int* __restrict__ idx_of,
    const float* __restrict__ Wm1, const float* __restrict__ bm1,
    const float* __restrict__ Wm2, const float* __restrict__ bm2,
    float* __restrict__ out)
{
    __shared__ float psum[4][HID];     // phase1 partials; reused as [2][HID] in phase2
    __shared__ float p[HID];
    __shared__ float red[HID];
    __shared__ int se[2];
    const int g = blockIdx.x, t = threadIdx.x;
    if (t < 2) {
        int target = g + t;
        int lo = 0, hi = N_NODES;
        while (lo < hi) { int mid = (lo + hi) >> 1; if (batch[mid] < target) lo = mid + 1; else hi = mid; }
        se[t] = lo;
    }
    __syncthreads();
    const int s = se[0], e = se[1];

    // ---- phase 1: pooled sums ----
    const int fp = t & 127;            // feature pair: feats 2fp, 2fp+1
    const int pl = t >> 7;             // node lane 0..3
    const unsigned short* hp = h + (size_t)(fp >> 6) * ((size_t)NPAD * 128) + ((2 * fp) & 127);
    float a0 = 0.f, a1 = 0.f;
    int n = s + pl;
    for (; n + 12 < e; n += 16) {      // 4 rows in flight per thread, stride 4
        int i0 = idx_of[n], i1 = idx_of[n + 4], i2 = idx_of[n + 8], i3 = idx_of[n + 12];
        unsigned u0 = *reinterpret_cast<const unsigned*>(hp + (size_t)i0 * 128);
        unsigned u1 = *reinterpret_cast<const unsigned*>(hp + (size_t)i1 * 128);
        unsigned u2 = *reinterpret_cast<const unsigned*>(hp + (size_t)i2 * 128);
        unsigned u3 = *reinterpret_cast<const unsigned*>(hp + (size_t)i3 * 128);
        a0 += (b2f_lo(u0) + b2f_lo(u1)) + (b2f_lo(u2) + b2f_lo(u3));
        a1 += (b2f_hi(u0) + b2f_hi(u1)) + (b2f_hi(u2) + b2f_hi(u3));
    }
    for (; n < e; n += 4) {
        unsigned u = *reinterpret_cast<const unsigned*>(hp + (size_t)idx_of[n] * 128);
        a0 += b2f_lo(u); a1 += b2f_hi(u);
    }
    psum[pl][2 * fp]     = a0;
    psum[pl][2 * fp + 1] = a1;
    __syncthreads();
    if (t < HID) {
        float inv = 1.0f / fmaxf((float)(e - s), 1.0f);
        p[t] = (psum[0][t] + psum[1][t] + psum[2][t] + psum[3][t]) * inv;
    }
    __syncthreads();

    // ---- phase 2: MLP, k-range split across 2 groups ----
    const int tt = t & 255, qq = t >> 8;
    const int k0 = qq * 128;
    float a2 = 0.f;
    for (int k = 0; k < 128; ++k)
        a2 = fmaf(p[k0 + k], Wm1[(k0 + k) * HID + tt], a2);
    psum[qq][tt] = a2;
    __syncthreads();
    if (t < HID)
        red[t] = fmaxf(psum[0][t] + psum[1][t] + bm1[t], 0.f) * Wm2[t];
    __syncthreads();
    for (int o = 128; o > 0; o >>= 1) {
        if (t < o) red[t] += red[t + o];
        __syncthreads();
    }
    if (t == 0) out[g] = red[0] + bm2[0];
}

// ---------------- launch ----------------
extern "C" void kernel_launch(void* const* d_in, const int* in_sizes, int n_in,
                              void* d_out, int out_size, void* d_ws, size_t ws_size,
                              hipStream_t stream) {
    const float* x    = (const float*)d_in[0];
    const int*   ei   = (const int*)d_in[1];
    const int*   batch= (const int*)d_in[2];
    const float* W0   = (const float*)d_in[3];
    const float* b0   = (const float*)d_in[4];
    const float* W1   = (const float*)d_in[5];
    const float* b1   = (const float*)d_in[6];
    const float* W2   = (const float*)d_in[7];
    const float* b2   = (const float*)d_in[8];
    const float* Wm1  = (const float*)d_in[9];
    const float* bm1  = (const float*)d_in[10];
    const float* Wm2  = (const float*)d_in[11];
    const float* bm2  = (const float*)d_in[12];
    float* out = (float*)d_out;

    char* ws = (char*)d_ws;
    size_t off = 0;
    auto alloc = [&](size_t bytes) -> void* {
        void* p = ws + off;
        off += (bytes + 255) & ~(size_t)255;
        return p;
    };
    int*   deg    = (int*)  alloc((size_t)N_NODES * 4);
    int*   bcnt   = (int*)  alloc(64 * 4);
    int*   bcur   = (int*)  alloc(64 * 4);
    float* dis    = (float*)alloc((size_t)N_NODES * 4);
    int*   row_st = (int*)  alloc((size_t)N_NODES * 4);
    int*   bsum   = (int*)  alloc((size_t)64 * 4);
    int*   seq    = (int*)  alloc((size_t)N_EDGES * 4);
    int4*  perm4  = (int4*) alloc((size_t)NPAD * 16);
    int*   idx_of = (int*)  alloc((size_t)N_NODES * 4);
    int2*  csr    = (int2*) alloc((size_t)N_EDGES * 8);
    unsigned short* x_bf  = (unsigned short*)alloc((size_t)NPAD * F_IN * 2);   // [2][NPAD][64] half-major
    unsigned short* Wt0   = (unsigned short*)alloc((size_t)F_IN * HID * 2);
    unsigned short* Wt1   = (unsigned short*)alloc((size_t)HID * HID * 2);
    unsigned short* Wt2   = (unsigned short*)alloc((size_t)HID * HID * 2);
    unsigned short* bufA  = (unsigned short*)alloc((size_t)NPAD * HID * 2);    // fragment layout
    unsigned short* bufB  = (unsigned short*)alloc((size_t)NPAD * HID * 2);    // [2][NPAD][128] half-major

    const int* src = ei;
    const int* dst = ei + N_EDGES;
    const int NB = (N_NODES + 1023) / 1024;   // 49

    // zero deg + bcnt + bcur (contiguous allocations)
    size_t zlen = (size_t)((char*)bcur - (char*)deg) + 64 * 4;
    hipMemsetAsync(deg, 0, zlen, stream);

    prep_kernel         <<<3765, 256, 0, stream>>>(dst, deg, seq, W0, W1, W2, Wt0, Wt1, Wt2);
    block_sum_dis_kernel<<<NB, 256, 0, stream>>>(deg, bsum, dis, bcnt, N_NODES);
    scan_bsum_kernel    <<<1, 64, 0, stream>>>(bsum, NB, bcnt, bcur);
    scan_local_kernel   <<<NB, 256, 0, stream>>>(deg, bsum, row_st, bcur, perm4, idx_of, dis, N_NODES);
    fillcsr_xconv_kernel<<<3125 + 782, 256, 0, stream>>>(src, dst, dis, idx_of, row_st, seq, csr,
                                                         x, perm4, x_bf);

    dim3 ggrid(NPAD / 128, 2);
    const int AGG_B = (N_NODES + 3) / 4;

    agg_split<F_IN><<<AGG_B * 2, 256, 0, stream>>>(x_bf, perm4, csr, (uint4*)bufA);
    gemm_frag<F_IN><<<ggrid, 256, 0, stream>>>((const uint4*)bufA, Wt0, b0, bufB, 1);

    agg_split<HID><<<AGG_B * 2, 256, 0, stream>>>(bufB, perm4, csr, (uint4*)bufA);
    gemm_frag<HID><<<ggrid, 256, 0, stream>>>((const uint4*)bufA, Wt1, b1, bufB, 1);

    agg_split<HID><<<AGG_B * 2, 256, 0, stream>>>(bufB, perm4, csr, (uint4*)bufA);
    gemm_frag<HID><<<ggrid, 256, 0, stream>>>((const uint4*)bufA, Wt2, b2, bufB, 1);

    pool_mlp_kernel<<<N_GRAPHS, 512, 0, stream>>>(bufB, batch, idx_of, Wm1, bm1, Wm2, bm2, out);
}